// Round 14
// baseline (102.477 us; speedup 1.0000x reference)
//
#include <hip/hip_runtime.h>
#include <hip/hip_bf16.h>

#define N 4096
#define HID 256
#define NH 8
#define HD 32
#define NC 784    // 256 Q | 256 K | 256 V | 16 EG
#define CH 16     // j-chunks; Vpb = CH*2MB
#define JSPAN (N / CH)

typedef __attribute__((ext_vector_type(8))) short short8;
typedef __attribute__((ext_vector_type(4))) short short4v;
typedef __attribute__((ext_vector_type(4))) float f32x4;
typedef __attribute__((ext_vector_type(2))) unsigned int uint2v;
typedef __attribute__((ext_vector_type(4))) unsigned int uint4v;

// Q scale = (1/sqrt(32)) * log2(e): folds softmax temp AND exp->exp2 conversion
#define QSCALE 0.25503482f

static __device__ __forceinline__ unsigned short f2bf(float f) {
    union { float f; unsigned u; } v; v.f = f;
    unsigned r = v.u + 0x7fff + ((v.u >> 16) & 1);
    return (unsigned short)(r >> 16);
}
static __device__ __forceinline__ float bf2f(unsigned short u) {
    union { unsigned u; float f; } v; v.u = ((unsigned)u) << 16; return v.f;
}
// 3-VALU round-half-up pack: lo16 = bf16(a), hi16 = bf16(b). Proven r12.
static __device__ __forceinline__ unsigned packhu(float a, float b) {
    unsigned ua = __builtin_bit_cast(unsigned, a) + 0x8000u;
    unsigned ub = __builtin_bit_cast(unsigned, b) + 0x8000u;
    return __builtin_amdgcn_perm(ub, ua, 0x07060302u);
}

// ---- fused prep: feat->bf16 (blocks 0..1023) | WbT/bC build + colS zero ----
__global__ void k_prep(const float* __restrict__ feat, const float* __restrict__ Wq,
                       const float* __restrict__ Wkv, const float* __restrict__ Weg,
                       const float* __restrict__ bq, const float* __restrict__ bkv,
                       const float* __restrict__ beg, unsigned short* __restrict__ featb,
                       unsigned short* __restrict__ WbT, float* __restrict__ bC,
                       float* __restrict__ colS) {
    int bx = blockIdx.x;
    if (bx < 1024) {
        int t = bx * 256 + threadIdx.x;
        float4 v = ((const float4*)feat)[t];
        short4v o;
        o[0] = (short)f2bf(v.x); o[1] = (short)f2bf(v.y);
        o[2] = (short)f2bf(v.z); o[3] = (short)f2bf(v.w);
        ((short4v*)featb)[t] = o;
    } else {
        int c = bx - 1024, k = threadIdx.x;
        float w, b;
        if (c < 256)      { w = Wq[k * 256 + c];          b = bq[c]; }
        else if (c < 768) { w = Wkv[k * 512 + (c - 256)]; b = bkv[c - 256]; }
        else              { w = Weg[k * 16 + (c - 768)];  b = beg[c - 768]; }
        WbT[c * 256 + k] = f2bf(w);
        if (k == 0) bC[c] = b;
        if (c < 128) colS[c * 256 + k] = 0.f;
    }
}

// ---- projection GEMM: [4096,256]x[256,784]; scatter into packed layouts ----
__global__ __launch_bounds__(256) void k_proj(const unsigned short* __restrict__ featb,
                                              const unsigned short* __restrict__ WbT,
                                              const float* __restrict__ bC,
                                              unsigned short* __restrict__ Qp,
                                              unsigned short* __restrict__ Kp,
                                              unsigned short* __restrict__ VpT,
                                              float* __restrict__ sigG) {
    int w = threadIdx.x >> 6, l = threadIdx.x & 63;
    int il = l & 15, g = l >> 4;
    int c0 = blockIdx.x * 16;
    int i0 = (blockIdx.y * 4 + w) * 16;
    const short8* Arow = (const short8*)(featb + (size_t)(i0 + il) * HID);
    const short8* Brow = (const short8*)(WbT + (size_t)(c0 + il) * HID);
    f32x4 acc = {0.f, 0.f, 0.f, 0.f};
#pragma unroll
    for (int k0 = 0; k0 < HID; k0 += 32) {
        short8 a = Arow[(k0 >> 3) + g];
        short8 b = Brow[(k0 >> 3) + g];
        acc = __builtin_amdgcn_mfma_f32_16x16x32_bf16(a, b, acc, 0, 0, 0);
    }
    int c = c0 + il;
    float bias = bC[c];
#pragma unroll
    for (int r = 0; r < 4; ++r) {
        int i = i0 + g * 4 + r;
        float val = acc[r] + bias;
        if (c < 256) {
            int h = c & 7, d = c >> 3;
            Qp[((size_t)h * N + i) * HD + d] = f2bf(val * QSCALE);
        } else if (c < 512) {
            int cc = c - 256, h = cc & 7, d = cc >> 3;
            Kp[((size_t)h * N + i) * HD + d] = f2bf(val);
        } else if (c < 768) {
            int cc = c - 512, h = cc & 7, d = cc >> 3;
            VpT[((size_t)h * HD + d) * N + i] = f2bf(val);
        } else {
            int cc = c - 768;
            if (cc >= 8) sigG[(size_t)(cc - 8) * N + i] = 1.f / (1.f + __expf(-val));
        }
    }
}

// ---- pass 1: colS[j,h] += sum_i 2^(S2_ij); 2-deep Q prefetch (r13) ----
// grid (16, NH, 32): x*4+w = j-tile of 64 (4 K-frags), z = i-chunk of 128
__global__ __launch_bounds__(256) void k_pass1(const unsigned short* __restrict__ Qp,
                                               const unsigned short* __restrict__ Kp,
                                               float* __restrict__ colS) {
    int w = threadIdx.x >> 6, l = threadIdx.x & 63;
    int il = l & 15, g = l >> 4;
    int h = blockIdx.y;
    int j0 = (blockIdx.x * 4 + w) * 64;
    const unsigned short* Kh = Kp + (size_t)h * N * HD;
    short8 Kf[4];
#pragma unroll
    for (int t = 0; t < 4; ++t)
        Kf[t] = *(const short8*)(Kh + (size_t)(j0 + 16 * t + il) * HD + g * 8);
    const unsigned short* Qh = Qp + (size_t)h * N * HD;
    f32x4 z = {0.f, 0.f, 0.f, 0.f};
    float s[4] = {0.f, 0.f, 0.f, 0.f};
    int ibeg = blockIdx.z * 128;
    short8 Qa0 = *(const short8*)(Qh + (size_t)(ibeg + il) * HD + g * 8);
    short8 Qb0 = *(const short8*)(Qh + (size_t)(ibeg + 16 + il) * HD + g * 8);
    short8 Qa1 = *(const short8*)(Qh + (size_t)(ibeg + 32 + il) * HD + g * 8);
    short8 Qb1 = *(const short8*)(Qh + (size_t)(ibeg + 48 + il) * HD + g * 8);
#pragma unroll
    for (int it = 0; it < 4; ++it) {
        int i0 = ibeg + it * 32;
        short8 cQa = Qa0, cQb = Qb0;
        Qa0 = Qa1; Qb0 = Qb1;
        int in = i0 + 64;   // unconditional 2-ahead prefetch; over-read stays in ws
        Qa1 = *(const short8*)(Qh + (size_t)(in + il) * HD + g * 8);
        Qb1 = *(const short8*)(Qh + (size_t)(in + 16 + il) * HD + g * 8);
        __builtin_amdgcn_sched_barrier(0);
#pragma unroll
        for (int t = 0; t < 4; ++t) {
            f32x4 Sa = __builtin_amdgcn_mfma_f32_16x16x32_bf16(cQa, Kf[t], z, 0, 0, 0);
            f32x4 Sb = __builtin_amdgcn_mfma_f32_16x16x32_bf16(cQb, Kf[t], z, 0, 0, 0);
            s[t] += ((__builtin_amdgcn_exp2f(Sa[0]) + __builtin_amdgcn_exp2f(Sa[1]))
                   + (__builtin_amdgcn_exp2f(Sa[2]) + __builtin_amdgcn_exp2f(Sa[3])))
                  + ((__builtin_amdgcn_exp2f(Sb[0]) + __builtin_amdgcn_exp2f(Sb[1]))
                   + (__builtin_amdgcn_exp2f(Sb[2]) + __builtin_amdgcn_exp2f(Sb[3])));
        }
    }
#pragma unroll
    for (int t = 0; t < 4; ++t) {
        s[t] += __shfl_xor(s[t], 16);
        s[t] += __shfl_xor(s[t], 32);
    }
    if (g == 0) {
#pragma unroll
        for (int t = 0; t < 4; ++t)
            atomicAdd(&colS[(size_t)h * N + j0 + 16 * t + il], s[t]);
    }
}

// Assemble PV A-frag in registers from swapped-QK outputs (layout proven r10).
static __device__ __forceinline__ short8 frag_dance(f32x4 Sa, f32x4 Sb) {
    unsigned A0 = packhu(__builtin_amdgcn_exp2f(Sa[0]), __builtin_amdgcn_exp2f(Sa[1]));
    unsigned A1 = packhu(__builtin_amdgcn_exp2f(Sa[2]), __builtin_amdgcn_exp2f(Sa[3]));
    unsigned B0 = packhu(__builtin_amdgcn_exp2f(Sb[0]), __builtin_amdgcn_exp2f(Sb[1]));
    unsigned B1 = packhu(__builtin_amdgcn_exp2f(Sb[2]), __builtin_amdgcn_exp2f(Sb[3]));
    uint2v r1 = __builtin_amdgcn_permlane32_swap(A0, B0, false, false);
    uint2v r2 = __builtin_amdgcn_permlane16_swap(r1[0], r1[1], false, false); // dw0, dw2
    uint2v r3 = __builtin_amdgcn_permlane32_swap(A1, B1, false, false);
    uint2v r4 = __builtin_amdgcn_permlane16_swap(r3[0], r3[1], false, false); // dw1, dw3
    uint4v pu;
    pu[0] = r2[0]; pu[1] = r4[0]; pu[2] = r2[1]; pu[3] = r4[1];
    return __builtin_bit_cast(short8, pu);
}

// ---- pass 2: LDS-staged K/V (XOR-swizzled), 4 waves share one j-chunk ----
// grid (16, NH, CH), 256 thr: wave w owns i-tile [bx*256+64w, +64).
// V scaled by sigG/colS during staging (k_vprep eliminated).
__global__ __launch_bounds__(256) void k_pass2(const unsigned short* __restrict__ Qp,
                                               const unsigned short* __restrict__ Kp,
                                               const unsigned short* __restrict__ VpT,
                                               const float* __restrict__ sigG,
                                               const float* __restrict__ colS,
                                               unsigned short* __restrict__ Vpb) {
    __shared__ __align__(16) char KsB[256 * 64];   // K[j][d] rows 64B, swz ^((j&7)<<4)
    __shared__ __align__(16) char VsB[32 * 512];   // V'[d][j] rows 512B, swz ^((d&7)<<4)
    int w = threadIdx.x >> 6, l = threadIdx.x & 63;
    int il = l & 15, g = l >> 4;
    int h = blockIdx.y;
    int i0 = blockIdx.x * 256 + w * 64;
    int jbeg = blockIdx.z * JSPAN;
    // ---- stage K: 1024 16B-chunks, coalesced global, swizzled LDS
    {
        const unsigned short* Kg = Kp + ((size_t)h * N + jbeg) * HD;
        int t = threadIdx.x;
#pragma unroll
        for (int p = 0; p < 4; ++p) {
            int cidx = t + p * 256;
            int j = cidx >> 2, ds = cidx & 3;
            uint4v val = *(const uint4v*)(Kg + (size_t)j * HD + ds * 8);
            *(uint4v*)(KsB + ((j * 64 + ds * 16) ^ ((j & 7) << 4))) = val;
        }
        // ---- stage V with c_j = sigG/colS scale
        const unsigned short* Vg = VpT + (size_t)h * HD * N + jbeg;
        const float* sg = sigG + (size_t)h * N + jbeg;
        const float* cs = colS + (size_t)h * N + jbeg;
#pragma unroll
        for (int p = 0; p < 4; ++p) {
            int cidx = t + p * 256;
            int d = cidx >> 5, j0 = (cidx & 31) * 8;
            short8 v = *(const short8*)(Vg + (size_t)d * N + j0);
            f32x4 s0 = *(const f32x4*)(sg + j0), s1 = *(const f32x4*)(sg + j0 + 4);
            f32x4 c0 = *(const f32x4*)(cs + j0), c1 = *(const f32x4*)(cs + j0 + 4);
            uint4v o;
            o[0] = packhu(bf2f((unsigned short)v[0]) * s0[0] / c0[0],
                          bf2f((unsigned short)v[1]) * s0[1] / c0[1]);
            o[1] = packhu(bf2f((unsigned short)v[2]) * s0[2] / c0[2],
                          bf2f((unsigned short)v[3]) * s0[3] / c0[3]);
            o[2] = packhu(bf2f((unsigned short)v[4]) * s1[0] / c1[0],
                          bf2f((unsigned short)v[5]) * s1[1] / c1[1]);
            o[3] = packhu(bf2f((unsigned short)v[6]) * s1[2] / c1[2],
                          bf2f((unsigned short)v[7]) * s1[3] / c1[3]);
            *(uint4v*)(VsB + ((d * 512 + j0 * 2) ^ ((d & 7) << 4))) = o;
        }
    }
    const unsigned short* Qh = Qp + (size_t)h * N * HD;
    short8 Qf[4];
#pragma unroll
    for (int q = 0; q < 4; ++q)
        Qf[q] = *(const short8*)(Qh + (size_t)(i0 + q * 16 + il) * HD + g * 8);
    __syncthreads();
    f32x4 z = {0.f, 0.f, 0.f, 0.f};
    f32x4 acc[4][2];
#pragma unroll
    for (int q = 0; q < 4; ++q) { acc[q][0] = z; acc[q][1] = z; }
    int sw = (il & 7) << 4;
    int kA = (il * 64 + g * 16) ^ sw;          // K frag lane addr (j-half0); +1024 half1
#pragma unroll
    for (int it = 0; it < 8; ++it) {
        int jb = it * 32;
        short8 cK0 = *(const short8*)(KsB + jb * 64 + kA);
        short8 cK1 = *(const short8*)(KsB + jb * 64 + 1024 + kA);
        int vo = (jb * 2 + g * 16) ^ sw;
        short8 cV0 = *(const short8*)(VsB + il * 512 + vo);
        short8 cV1 = *(const short8*)(VsB + il * 512 + 8192 + vo);
#pragma unroll
        for (int q = 0; q < 4; ++q) {
            // swapped QK: lane(il,g) gets S[j=4g+r][i=il]
            f32x4 SA = __builtin_amdgcn_mfma_f32_16x16x32_bf16(cK0, Qf[q], z, 0, 0, 0);
            f32x4 SB = __builtin_amdgcn_mfma_f32_16x16x32_bf16(cK1, Qf[q], z, 0, 0, 0);
            short8 Pa = frag_dance(SA, SB);
            acc[q][0] = __builtin_amdgcn_mfma_f32_16x16x32_bf16(Pa, cV0, acc[q][0], 0, 0, 0);
            acc[q][1] = __builtin_amdgcn_mfma_f32_16x16x32_bf16(Pa, cV1, acc[q][1], 0, 0, 0);
        }
    }
    unsigned short* Vout = Vpb + (size_t)(blockIdx.z * NH + h) * N * HD;
#pragma unroll
    for (int q = 0; q < 4; ++q) {
#pragma unroll
        for (int r = 0; r < 4; ++r) {
            int ia = i0 + q * 16 + g * 4 + r;
            Vout[(size_t)ia * HD + il]      = f2bf(acc[q][0][r]);
            Vout[(size_t)ia * HD + 16 + il] = f2bf(acc[q][1][r]);
        }
    }
}

// ---- layernorm: sum CH bf16 partials (layout [ch][h][i][d]), normalize ----
__global__ __launch_bounds__(256) void k_ln(const unsigned short* __restrict__ Vpb,
                                            const float* __restrict__ gam,
                                            const float* __restrict__ bet,
                                            float* __restrict__ out) {
    int w = threadIdx.x >> 6, l = threadIdx.x & 63;
    int i = blockIdx.x * 4 + w;
    int h = l >> 3, d0 = (l & 7) << 2;   // lane owns channels c = (d0+r)*8 + h
    f32x4 x = {0.f, 0.f, 0.f, 0.f};
#pragma unroll
    for (int c = 0; c < CH; ++c) {
        short4v v = *(const short4v*)(Vpb + ((size_t)(c * NH + h) * N + i) * HD + d0);
        x[0] += bf2f((unsigned short)v[0]); x[1] += bf2f((unsigned short)v[1]);
        x[2] += bf2f((unsigned short)v[2]); x[3] += bf2f((unsigned short)v[3]);
    }
    float s1 = x[0] + x[1] + x[2] + x[3];
    float s2 = x[0] * x[0] + x[1] * x[1] + x[2] * x[2] + x[3] * x[3];
#pragma unroll
    for (int off = 1; off < 64; off <<= 1) {
        s1 += __shfl_xor(s1, off);
        s2 += __shfl_xor(s2, off);
    }
    float mu = s1 * (1.f / 256.f);
    float var = s2 * (1.f / 256.f) - mu * mu;
    float rs = rsqrtf(var + 1e-3f);
#pragma unroll
    for (int r = 0; r < 4; ++r) {
        int c = (d0 + r) * 8 + h;
        out[(size_t)i * HID + c] = (x[r] - mu) * rs * gam[c] + bet[c];
    }
}

extern "C" void kernel_launch(void* const* d_in, const int* in_sizes, int n_in,
                              void* d_out, int out_size, void* d_ws, size_t ws_size,
                              hipStream_t stream) {
    const float* feat = (const float*)d_in[0];
    const float* Wq   = (const float*)d_in[1];
    const float* bq   = (const float*)d_in[2];
    const float* Wkv  = (const float*)d_in[3];
    const float* bkv  = (const float*)d_in[4];
    const float* Weg  = (const float*)d_in[5];
    const float* beg  = (const float*)d_in[6];
    const float* ln_g = (const float*)d_in[7];
    const float* ln_b = (const float*)d_in[8];
    float* out = (float*)d_out;

    char* ws = (char*)d_ws;
    unsigned short* Qp    = (unsigned short*)(ws + 0);                     // 2 MB
    unsigned short* Kp    = (unsigned short*)(ws + (2u << 20));            // 2 MB
    unsigned short* VpT   = (unsigned short*)(ws + (4u << 20));            // 2 MB
    unsigned short* featb = (unsigned short*)(ws + (6u << 20));            // 2 MB
    unsigned short* WbT   = (unsigned short*)(ws + (8u << 20));            // 0.4 MB
    float* bC   = (float*)(ws + (8u << 20) + (512u << 10));                // 3 KB
    float* sigG = (float*)(ws + (8u << 20) + (528u << 10));                // 128 KB
    float* colS = (float*)(ws + (8u << 20) + (656u << 10));                // 128 KB
    unsigned short* Vpb = (unsigned short*)(ws + (9u << 20));              // CH*2 MB = 32 MB

    k_prep<<<dim3(1024 + NC), 256, 0, stream>>>(feat, Wq, Wkv, Weg, bq, bkv, beg,
                                                featb, WbT, bC, colS);
    k_proj<<<dim3(49, 64), 256, 0, stream>>>(featb, WbT, bC, Qp, Kp, VpT, sigG);
    k_pass1<<<dim3(16, NH, 32), 256, 0, stream>>>(Qp, Kp, colS);
    k_pass2<<<dim3(16, NH, CH), 256, 0, stream>>>(Qp, Kp, VpT, sigG, colS, Vpb);
    k_ln<<<dim3(1024), 256, 0, stream>>>(Vpb, ln_g, ln_b, out);
}

// Round 15
// 99.275 us; speedup vs baseline: 1.0323x; 1.0323x over previous
//
#include <hip/hip_runtime.h>
#include <hip/hip_bf16.h>

#define N 4096
#define HID 256
#define NH 8
#define HD 32
#define NC 784    // 256 Q | 256 K | 256 V | 16 EG
#define CH 16     // j-chunks; Vpb = CH*2MB
#define JSPAN (N / CH)

typedef __attribute__((ext_vector_type(8))) short short8;
typedef __attribute__((ext_vector_type(4))) short short4v;
typedef __attribute__((ext_vector_type(4))) float f32x4;
typedef __attribute__((ext_vector_type(2))) unsigned int uint2v;
typedef __attribute__((ext_vector_type(4))) unsigned int uint4v;

// Q scale = (1/sqrt(32)) * log2(e): folds softmax temp AND exp->exp2 conversion
#define QSCALE 0.25503482f

static __device__ __forceinline__ unsigned short f2bf(float f) {
    union { float f; unsigned u; } v; v.f = f;
    unsigned r = v.u + 0x7fff + ((v.u >> 16) & 1);
    return (unsigned short)(r >> 16);
}
static __device__ __forceinline__ float bf2f(unsigned short u) {
    union { unsigned u; float f; } v; v.u = ((unsigned)u) << 16; return v.f;
}
// 3-VALU round-half-up pack: lo16 = bf16(a), hi16 = bf16(b). Proven r12.
static __device__ __forceinline__ unsigned packhu(float a, float b) {
    unsigned ua = __builtin_bit_cast(unsigned, a) + 0x8000u;
    unsigned ub = __builtin_bit_cast(unsigned, b) + 0x8000u;
    return __builtin_amdgcn_perm(ub, ua, 0x07060302u);
}

// ---- fused prep: feat->bf16 (blocks 0..1023) | WbT/bC build + colS zero ----
__global__ void k_prep(const float* __restrict__ feat, const float* __restrict__ Wq,
                       const float* __restrict__ Wkv, const float* __restrict__ Weg,
                       const float* __restrict__ bq, const float* __restrict__ bkv,
                       const float* __restrict__ beg, unsigned short* __restrict__ featb,
                       unsigned short* __restrict__ WbT, float* __restrict__ bC,
                       float* __restrict__ colS) {
    int bx = blockIdx.x;
    if (bx < 1024) {
        int t = bx * 256 + threadIdx.x;
        float4 v = ((const float4*)feat)[t];
        short4v o;
        o[0] = (short)f2bf(v.x); o[1] = (short)f2bf(v.y);
        o[2] = (short)f2bf(v.z); o[3] = (short)f2bf(v.w);
        ((short4v*)featb)[t] = o;
    } else {
        int c = bx - 1024, k = threadIdx.x;
        float w, b;
        if (c < 256)      { w = Wq[k * 256 + c];          b = bq[c]; }
        else if (c < 768) { w = Wkv[k * 512 + (c - 256)]; b = bkv[c - 256]; }
        else              { w = Weg[k * 16 + (c - 768)];  b = beg[c - 768]; }
        WbT[c * 256 + k] = f2bf(w);
        if (k == 0) bC[c] = b;
        if (c < 128) colS[c * 256 + k] = 0.f;
    }
}

// ---- projection GEMM: [4096,256]x[256,784]; scatter into packed layouts ----
__global__ __launch_bounds__(256) void k_proj(const unsigned short* __restrict__ featb,
                                              const unsigned short* __restrict__ WbT,
                                              const float* __restrict__ bC,
                                              unsigned short* __restrict__ Qp,
                                              unsigned short* __restrict__ Kp,
                                              unsigned short* __restrict__ VpT,
                                              float* __restrict__ sigG) {
    int w = threadIdx.x >> 6, l = threadIdx.x & 63;
    int il = l & 15, g = l >> 4;
    int c0 = blockIdx.x * 16;
    int i0 = (blockIdx.y * 4 + w) * 16;
    const short8* Arow = (const short8*)(featb + (size_t)(i0 + il) * HID);
    const short8* Brow = (const short8*)(WbT + (size_t)(c0 + il) * HID);
    f32x4 acc = {0.f, 0.f, 0.f, 0.f};
#pragma unroll
    for (int k0 = 0; k0 < HID; k0 += 32) {
        short8 a = Arow[(k0 >> 3) + g];
        short8 b = Brow[(k0 >> 3) + g];
        acc = __builtin_amdgcn_mfma_f32_16x16x32_bf16(a, b, acc, 0, 0, 0);
    }
    int c = c0 + il;
    float bias = bC[c];
#pragma unroll
    for (int r = 0; r < 4; ++r) {
        int i = i0 + g * 4 + r;
        float val = acc[r] + bias;
        if (c < 256) {
            int h = c & 7, d = c >> 3;
            Qp[((size_t)h * N + i) * HD + d] = f2bf(val * QSCALE);
        } else if (c < 512) {
            int cc = c - 256, h = cc & 7, d = cc >> 3;
            Kp[((size_t)h * N + i) * HD + d] = f2bf(val);
        } else if (c < 768) {
            int cc = c - 512, h = cc & 7, d = cc >> 3;
            VpT[((size_t)h * HD + d) * N + i] = f2bf(val);
        } else {
            int cc = c - 768;
            if (cc >= 8) sigG[(size_t)(cc - 8) * N + i] = 1.f / (1.f + __expf(-val));
        }
    }
}

// ---- pass 1: colS[j,h] += sum_i 2^(S2_ij); 2-deep Q prefetch (r13) ----
// grid (16, NH, 32): x*4+w = j-tile of 64 (4 K-frags), z = i-chunk of 128
__global__ __launch_bounds__(256) void k_pass1(const unsigned short* __restrict__ Qp,
                                               const unsigned short* __restrict__ Kp,
                                               float* __restrict__ colS) {
    int w = threadIdx.x >> 6, l = threadIdx.x & 63;
    int il = l & 15, g = l >> 4;
    int h = blockIdx.y;
    int j0 = (blockIdx.x * 4 + w) * 64;
    const unsigned short* Kh = Kp + (size_t)h * N * HD;
    short8 Kf[4];
#pragma unroll
    for (int t = 0; t < 4; ++t)
        Kf[t] = *(const short8*)(Kh + (size_t)(j0 + 16 * t + il) * HD + g * 8);
    const unsigned short* Qh = Qp + (size_t)h * N * HD;
    f32x4 z = {0.f, 0.f, 0.f, 0.f};
    float s[4] = {0.f, 0.f, 0.f, 0.f};
    int ibeg = blockIdx.z * 128;
    short8 Qa0 = *(const short8*)(Qh + (size_t)(ibeg + il) * HD + g * 8);
    short8 Qb0 = *(const short8*)(Qh + (size_t)(ibeg + 16 + il) * HD + g * 8);
    short8 Qa1 = *(const short8*)(Qh + (size_t)(ibeg + 32 + il) * HD + g * 8);
    short8 Qb1 = *(const short8*)(Qh + (size_t)(ibeg + 48 + il) * HD + g * 8);
#pragma unroll
    for (int it = 0; it < 4; ++it) {
        int i0 = ibeg + it * 32;
        short8 cQa = Qa0, cQb = Qb0;
        Qa0 = Qa1; Qb0 = Qb1;
        int in = i0 + 64;   // unconditional 2-ahead prefetch; over-read stays in ws
        Qa1 = *(const short8*)(Qh + (size_t)(in + il) * HD + g * 8);
        Qb1 = *(const short8*)(Qh + (size_t)(in + 16 + il) * HD + g * 8);
        __builtin_amdgcn_sched_barrier(0);
#pragma unroll
        for (int t = 0; t < 4; ++t) {
            f32x4 Sa = __builtin_amdgcn_mfma_f32_16x16x32_bf16(cQa, Kf[t], z, 0, 0, 0);
            f32x4 Sb = __builtin_amdgcn_mfma_f32_16x16x32_bf16(cQb, Kf[t], z, 0, 0, 0);
            s[t] += ((__builtin_amdgcn_exp2f(Sa[0]) + __builtin_amdgcn_exp2f(Sa[1]))
                   + (__builtin_amdgcn_exp2f(Sa[2]) + __builtin_amdgcn_exp2f(Sa[3])))
                  + ((__builtin_amdgcn_exp2f(Sb[0]) + __builtin_amdgcn_exp2f(Sb[1]))
                   + (__builtin_amdgcn_exp2f(Sb[2]) + __builtin_amdgcn_exp2f(Sb[3])));
        }
    }
#pragma unroll
    for (int t = 0; t < 4; ++t) {
        s[t] += __shfl_xor(s[t], 16);
        s[t] += __shfl_xor(s[t], 32);
    }
    if (g == 0) {
#pragma unroll
        for (int t = 0; t < 4; ++t)
            atomicAdd(&colS[(size_t)h * N + j0 + 16 * t + il], s[t]);
    }
}

// ---- V-prescale (in place): V' = V * sigG * rcp(colS); rcp not full div ----
__global__ void k_vprep(unsigned short* __restrict__ VpT,
                        const float* __restrict__ sigG,
                        const float* __restrict__ colS) {
    int row = blockIdx.x >> 1;
    int j0 = ((blockIdx.x & 1) * 256 + threadIdx.x) * 8;
    int h = row >> 5;
    unsigned short* p = VpT + (size_t)row * N + j0;
    short8 v = *(short8*)p;
    const float* sg = sigG + (size_t)h * N + j0;
    const float* cs = colS + (size_t)h * N + j0;
    float sc[8];
#pragma unroll
    for (int k = 0; k < 8; ++k)
        sc[k] = sg[k] * __builtin_amdgcn_rcpf(cs[k]);
    uint4v ov;
    ov[0] = packhu(bf2f((unsigned short)v[0]) * sc[0], bf2f((unsigned short)v[1]) * sc[1]);
    ov[1] = packhu(bf2f((unsigned short)v[2]) * sc[2], bf2f((unsigned short)v[3]) * sc[3]);
    ov[2] = packhu(bf2f((unsigned short)v[4]) * sc[4], bf2f((unsigned short)v[5]) * sc[5]);
    ov[3] = packhu(bf2f((unsigned short)v[6]) * sc[6], bf2f((unsigned short)v[7]) * sc[7]);
    *(uint4v*)p = ov;
}

// Assemble PV A-frag in registers from swapped-QK outputs (layout proven r10).
static __device__ __forceinline__ short8 frag_dance(f32x4 Sa, f32x4 Sb) {
    unsigned A0 = packhu(__builtin_amdgcn_exp2f(Sa[0]), __builtin_amdgcn_exp2f(Sa[1]));
    unsigned A1 = packhu(__builtin_amdgcn_exp2f(Sa[2]), __builtin_amdgcn_exp2f(Sa[3]));
    unsigned B0 = packhu(__builtin_amdgcn_exp2f(Sb[0]), __builtin_amdgcn_exp2f(Sb[1]));
    unsigned B1 = packhu(__builtin_amdgcn_exp2f(Sb[2]), __builtin_amdgcn_exp2f(Sb[3]));
    uint2v r1 = __builtin_amdgcn_permlane32_swap(A0, B0, false, false);
    uint2v r2 = __builtin_amdgcn_permlane16_swap(r1[0], r1[1], false, false); // dw0, dw2
    uint2v r3 = __builtin_amdgcn_permlane32_swap(A1, B1, false, false);
    uint2v r4 = __builtin_amdgcn_permlane16_swap(r3[0], r3[1], false, false); // dw1, dw3
    uint4v pu;
    pu[0] = r2[0]; pu[1] = r4[0]; pu[2] = r2[1]; pu[3] = r4[1];
    return __builtin_bit_cast(short8, pu);
}

// ---- pass 2: Vpb[z][h][i][d] (bf16) = sum_{j in chunk} 2^(S2_ij) * V'[j,d] ----
// grid (16, NH, CH), 128-thr blocks: wave w owns i-tile [bx*256+128w, +128)
// (8 Q-frags = 2x compute per K/V load vs r12). 1-deep prefetch + setprio.
__global__ __launch_bounds__(128) void k_pass2(const unsigned short* __restrict__ Qp,
                                               const unsigned short* __restrict__ Kp,
                                               const unsigned short* __restrict__ VpT,
                                               unsigned short* __restrict__ Vpb) {
    int w = threadIdx.x >> 6, l = threadIdx.x & 63;
    int il = l & 15, g = l >> 4;
    int h = blockIdx.y;
    int i0 = blockIdx.x * 256 + w * 128;
    int jbeg = blockIdx.z * JSPAN;
    const unsigned short* Qh = Qp + (size_t)h * N * HD;
    const unsigned short* Kh = Kp + ((size_t)h * N + jbeg) * HD;
    const unsigned short* Vh = VpT + (size_t)h * HD * N + jbeg;
    short8 Qf[8];
#pragma unroll
    for (int q = 0; q < 8; ++q)
        Qf[q] = *(const short8*)(Qh + (size_t)(i0 + q * 16 + il) * HD + g * 8);
    f32x4 z = {0.f, 0.f, 0.f, 0.f};
    f32x4 acc[8][2];
#pragma unroll
    for (int q = 0; q < 8; ++q) { acc[q][0] = z; acc[q][1] = z; }
    // prologue: load jb = 0 operands
    short8 K0 = *(const short8*)(Kh + (size_t)il * HD + g * 8);
    short8 K1 = *(const short8*)(Kh + (size_t)(16 + il) * HD + g * 8);
    short8 V0 = *(const short8*)(Vh + (size_t)il * N + g * 8);
    short8 V1 = *(const short8*)(Vh + (size_t)(16 + il) * N + g * 8);
#pragma unroll
    for (int it = 0; it < 8; ++it) {
        int jb = it * 32;
        short8 cK0 = K0, cK1 = K1, cV0 = V0, cV1 = V1;
        int jn = jb + 32;   // unconditional prefetch; over-read stays in ws (safe)
        K0 = *(const short8*)(Kh + (size_t)(jn + il) * HD + g * 8);
        K1 = *(const short8*)(Kh + (size_t)(jn + 16 + il) * HD + g * 8);
        V0 = *(const short8*)(Vh + (size_t)il * N + jn + g * 8);
        V1 = *(const short8*)(Vh + (size_t)(16 + il) * N + jn + g * 8);
        __builtin_amdgcn_sched_barrier(0);   // pin prefetch above compute
        __builtin_amdgcn_s_setprio(1);
#pragma unroll
        for (int q = 0; q < 8; ++q) {
            // swapped QK: lane(il,g) gets S[j=4g+r][i=il]
            f32x4 SA = __builtin_amdgcn_mfma_f32_16x16x32_bf16(cK0, Qf[q], z, 0, 0, 0);
            f32x4 SB = __builtin_amdgcn_mfma_f32_16x16x32_bf16(cK1, Qf[q], z, 0, 0, 0);
            short8 Pa = frag_dance(SA, SB);
            acc[q][0] = __builtin_amdgcn_mfma_f32_16x16x32_bf16(Pa, cV0, acc[q][0], 0, 0, 0);
            acc[q][1] = __builtin_amdgcn_mfma_f32_16x16x32_bf16(Pa, cV1, acc[q][1], 0, 0, 0);
        }
        __builtin_amdgcn_s_setprio(0);
    }
    unsigned short* Vout = Vpb + (size_t)(blockIdx.z * NH + h) * N * HD;
#pragma unroll
    for (int q = 0; q < 8; ++q) {
#pragma unroll
        for (int r = 0; r < 4; ++r) {
            int ia = i0 + q * 16 + g * 4 + r;
            Vout[(size_t)ia * HD + il]      = f2bf(acc[q][0][r]);
            Vout[(size_t)ia * HD + 16 + il] = f2bf(acc[q][1][r]);
        }
    }
}

// ---- layernorm: sum CH bf16 partials (layout [ch][h][i][d]), normalize ----
__global__ __launch_bounds__(256) void k_ln(const unsigned short* __restrict__ Vpb,
                                            const float* __restrict__ gam,
                                            const float* __restrict__ bet,
                                            float* __restrict__ out) {
    int w = threadIdx.x >> 6, l = threadIdx.x & 63;
    int i = blockIdx.x * 4 + w;
    int h = l >> 3, d0 = (l & 7) << 2;   // lane owns channels c = (d0+r)*8 + h
    f32x4 x = {0.f, 0.f, 0.f, 0.f};
#pragma unroll
    for (int c = 0; c < CH; ++c) {
        short4v v = *(const short4v*)(Vpb + ((size_t)(c * NH + h) * N + i) * HD + d0);
        x[0] += bf2f((unsigned short)v[0]); x[1] += bf2f((unsigned short)v[1]);
        x[2] += bf2f((unsigned short)v[2]); x[3] += bf2f((unsigned short)v[3]);
    }
    float s1 = x[0] + x[1] + x[2] + x[3];
    float s2 = x[0] * x[0] + x[1] * x[1] + x[2] * x[2] + x[3] * x[3];
#pragma unroll
    for (int off = 1; off < 64; off <<= 1) {
        s1 += __shfl_xor(s1, off);
        s2 += __shfl_xor(s2, off);
    }
    float mu = s1 * (1.f / 256.f);
    float var = s2 * (1.f / 256.f) - mu * mu;
    float rs = rsqrtf(var + 1e-3f);
#pragma unroll
    for (int r = 0; r < 4; ++r) {
        int c = (d0 + r) * 8 + h;
        out[(size_t)i * HID + c] = (x[r] - mu) * rs * gam[c] + bet[c];
    }
}

extern "C" void kernel_launch(void* const* d_in, const int* in_sizes, int n_in,
                              void* d_out, int out_size, void* d_ws, size_t ws_size,
                              hipStream_t stream) {
    const float* feat = (const float*)d_in[0];
    const float* Wq   = (const float*)d_in[1];
    const float* bq   = (const float*)d_in[2];
    const float* Wkv  = (const float*)d_in[3];
    const float* bkv  = (const float*)d_in[4];
    const float* Weg  = (const float*)d_in[5];
    const float* beg  = (const float*)d_in[6];
    const float* ln_g = (const float*)d_in[7];
    const float* ln_b = (const float*)d_in[8];
    float* out = (float*)d_out;

    char* ws = (char*)d_ws;
    unsigned short* Qp    = (unsigned short*)(ws + 0);                     // 2 MB
    unsigned short* Kp    = (unsigned short*)(ws + (2u << 20));            // 2 MB
    unsigned short* VpT   = (unsigned short*)(ws + (4u << 20));            // 2 MB
    unsigned short* featb = (unsigned short*)(ws + (6u << 20));            // 2 MB
    unsigned short* WbT   = (unsigned short*)(ws + (8u << 20));            // 0.4 MB
    float* bC   = (float*)(ws + (8u << 20) + (512u << 10));                // 3 KB
    float* sigG = (float*)(ws + (8u << 20) + (528u << 10));                // 128 KB
    float* colS = (float*)(ws + (8u << 20) + (656u << 10));                // 128 KB
    unsigned short* Vpb = (unsigned short*)(ws + (9u << 20));              // CH*2 MB = 32 MB

    k_prep<<<dim3(1024 + NC), 256, 0, stream>>>(feat, Wq, Wkv, Weg, bq, bkv, beg,
                                                featb, WbT, bC, colS);
    k_proj<<<dim3(49, 64), 256, 0, stream>>>(featb, WbT, bC, Qp, Kp, VpT, sigG);
    k_pass1<<<dim3(16, NH, 32), 256, 0, stream>>>(Qp, Kp, colS);
    k_vprep<<<dim3(512), 256, 0, stream>>>(VpT, sigG, colS);
    k_pass2<<<dim3(16, NH, CH), 128, 0, stream>>>(Qp, Kp, VpT, Vpb);
    k_ln<<<dim3(1024), 256, 0, stream>>>(Vpb, ln_g, ln_b, out);
}

// Round 16
// 97.564 us; speedup vs baseline: 1.0504x; 1.0175x over previous
//
#include <hip/hip_runtime.h>
#include <hip/hip_bf16.h>

#define N 4096
#define HID 256
#define NH 8
#define HD 32
#define NC 784    // 256 Q | 256 K | 256 V | 16 EG
#define CH 16     // j-chunks; Vpb = CH*2MB
#define JSPAN (N / CH)

typedef __attribute__((ext_vector_type(8))) short short8;
typedef __attribute__((ext_vector_type(4))) short short4v;
typedef __attribute__((ext_vector_type(4))) float f32x4;
typedef __attribute__((ext_vector_type(2))) unsigned int uint2v;
typedef __attribute__((ext_vector_type(4))) unsigned int uint4v;

// Q scale = (1/sqrt(32)) * log2(e): folds softmax temp AND exp->exp2 conversion
#define QSCALE 0.25503482f

// async DMA global->LDS, 16B per lane, LDS dst = wave-uniform base + lane*16
#define GLOAD(gp, sp) __builtin_amdgcn_global_load_lds( \
    (const __attribute__((address_space(1))) unsigned int*)(gp), \
    (__attribute__((address_space(3))) unsigned int*)(sp), 16, 0, 0)

static __device__ __forceinline__ unsigned short f2bf(float f) {
    union { float f; unsigned u; } v; v.f = f;
    unsigned r = v.u + 0x7fff + ((v.u >> 16) & 1);
    return (unsigned short)(r >> 16);
}
static __device__ __forceinline__ float bf2f(unsigned short u) {
    union { unsigned u; float f; } v; v.u = ((unsigned)u) << 16; return v.f;
}
// 3-VALU round-half-up pack: lo16 = bf16(a), hi16 = bf16(b). Proven r12.
static __device__ __forceinline__ unsigned packhu(float a, float b) {
    unsigned ua = __builtin_bit_cast(unsigned, a) + 0x8000u;
    unsigned ub = __builtin_bit_cast(unsigned, b) + 0x8000u;
    return __builtin_amdgcn_perm(ub, ua, 0x07060302u);
}

// ---- fused prep: feat->bf16 (blocks 0..1023) | WbT/bC build + colS zero ----
__global__ void k_prep(const float* __restrict__ feat, const float* __restrict__ Wq,
                       const float* __restrict__ Wkv, const float* __restrict__ Weg,
                       const float* __restrict__ bq, const float* __restrict__ bkv,
                       const float* __restrict__ beg, unsigned short* __restrict__ featb,
                       unsigned short* __restrict__ WbT, float* __restrict__ bC,
                       float* __restrict__ colS) {
    int bx = blockIdx.x;
    if (bx < 1024) {
        int t = bx * 256 + threadIdx.x;
        float4 v = ((const float4*)feat)[t];
        short4v o;
        o[0] = (short)f2bf(v.x); o[1] = (short)f2bf(v.y);
        o[2] = (short)f2bf(v.z); o[3] = (short)f2bf(v.w);
        ((short4v*)featb)[t] = o;
    } else {
        int c = bx - 1024, k = threadIdx.x;
        float w, b;
        if (c < 256)      { w = Wq[k * 256 + c];          b = bq[c]; }
        else if (c < 768) { w = Wkv[k * 512 + (c - 256)]; b = bkv[c - 256]; }
        else              { w = Weg[k * 16 + (c - 768)];  b = beg[c - 768]; }
        WbT[c * 256 + k] = f2bf(w);
        if (k == 0) bC[c] = b;
        if (c < 128) colS[c * 256 + k] = 0.f;
    }
}

// ---- projection GEMM: [4096,256]x[256,784]; scatter into packed layouts ----
__global__ __launch_bounds__(256) void k_proj(const unsigned short* __restrict__ featb,
                                              const unsigned short* __restrict__ WbT,
                                              const float* __restrict__ bC,
                                              unsigned short* __restrict__ Qp,
                                              unsigned short* __restrict__ Kp,
                                              unsigned short* __restrict__ VpT,
                                              float* __restrict__ sigG) {
    int w = threadIdx.x >> 6, l = threadIdx.x & 63;
    int il = l & 15, g = l >> 4;
    int c0 = blockIdx.x * 16;
    int i0 = (blockIdx.y * 4 + w) * 16;
    const short8* Arow = (const short8*)(featb + (size_t)(i0 + il) * HID);
    const short8* Brow = (const short8*)(WbT + (size_t)(c0 + il) * HID);
    f32x4 acc = {0.f, 0.f, 0.f, 0.f};
#pragma unroll
    for (int k0 = 0; k0 < HID; k0 += 32) {
        short8 a = Arow[(k0 >> 3) + g];
        short8 b = Brow[(k0 >> 3) + g];
        acc = __builtin_amdgcn_mfma_f32_16x16x32_bf16(a, b, acc, 0, 0, 0);
    }
    int c = c0 + il;
    float bias = bC[c];
#pragma unroll
    for (int r = 0; r < 4; ++r) {
        int i = i0 + g * 4 + r;
        float val = acc[r] + bias;
        if (c < 256) {
            int h = c & 7, d = c >> 3;
            Qp[((size_t)h * N + i) * HD + d] = f2bf(val * QSCALE);
        } else if (c < 512) {
            int cc = c - 256, h = cc & 7, d = cc >> 3;
            Kp[((size_t)h * N + i) * HD + d] = f2bf(val);
        } else if (c < 768) {
            int cc = c - 512, h = cc & 7, d = cc >> 3;
            VpT[((size_t)h * HD + d) * N + i] = f2bf(val);
        } else {
            int cc = c - 768;
            if (cc >= 8) sigG[(size_t)(cc - 8) * N + i] = 1.f / (1.f + __expf(-val));
        }
    }
}

// ---- pass 1: colS[j,h] += sum_i 2^(S2_ij); 2-deep Q prefetch (r13) ----
// grid (16, NH, 32): x*4+w = j-tile of 64 (4 K-frags), z = i-chunk of 128
__global__ __launch_bounds__(256) void k_pass1(const unsigned short* __restrict__ Qp,
                                               const unsigned short* __restrict__ Kp,
                                               float* __restrict__ colS) {
    int w = threadIdx.x >> 6, l = threadIdx.x & 63;
    int il = l & 15, g = l >> 4;
    int h = blockIdx.y;
    int j0 = (blockIdx.x * 4 + w) * 64;
    const unsigned short* Kh = Kp + (size_t)h * N * HD;
    short8 Kf[4];
#pragma unroll
    for (int t = 0; t < 4; ++t)
        Kf[t] = *(const short8*)(Kh + (size_t)(j0 + 16 * t + il) * HD + g * 8);
    const unsigned short* Qh = Qp + (size_t)h * N * HD;
    f32x4 z = {0.f, 0.f, 0.f, 0.f};
    float s[4] = {0.f, 0.f, 0.f, 0.f};
    int ibeg = blockIdx.z * 128;
    short8 Qa0 = *(const short8*)(Qh + (size_t)(ibeg + il) * HD + g * 8);
    short8 Qb0 = *(const short8*)(Qh + (size_t)(ibeg + 16 + il) * HD + g * 8);
    short8 Qa1 = *(const short8*)(Qh + (size_t)(ibeg + 32 + il) * HD + g * 8);
    short8 Qb1 = *(const short8*)(Qh + (size_t)(ibeg + 48 + il) * HD + g * 8);
#pragma unroll
    for (int it = 0; it < 4; ++it) {
        int i0 = ibeg + it * 32;
        short8 cQa = Qa0, cQb = Qb0;
        Qa0 = Qa1; Qb0 = Qb1;
        int in = i0 + 64;   // unconditional 2-ahead prefetch; over-read stays in ws
        Qa1 = *(const short8*)(Qh + (size_t)(in + il) * HD + g * 8);
        Qb1 = *(const short8*)(Qh + (size_t)(in + 16 + il) * HD + g * 8);
        __builtin_amdgcn_sched_barrier(0);
#pragma unroll
        for (int t = 0; t < 4; ++t) {
            f32x4 Sa = __builtin_amdgcn_mfma_f32_16x16x32_bf16(cQa, Kf[t], z, 0, 0, 0);
            f32x4 Sb = __builtin_amdgcn_mfma_f32_16x16x32_bf16(cQb, Kf[t], z, 0, 0, 0);
            s[t] += ((__builtin_amdgcn_exp2f(Sa[0]) + __builtin_amdgcn_exp2f(Sa[1]))
                   + (__builtin_amdgcn_exp2f(Sa[2]) + __builtin_amdgcn_exp2f(Sa[3])))
                  + ((__builtin_amdgcn_exp2f(Sb[0]) + __builtin_amdgcn_exp2f(Sb[1]))
                   + (__builtin_amdgcn_exp2f(Sb[2]) + __builtin_amdgcn_exp2f(Sb[3])));
        }
    }
#pragma unroll
    for (int t = 0; t < 4; ++t) {
        s[t] += __shfl_xor(s[t], 16);
        s[t] += __shfl_xor(s[t], 32);
    }
    if (g == 0) {
#pragma unroll
        for (int t = 0; t < 4; ++t)
            atomicAdd(&colS[(size_t)h * N + j0 + 16 * t + il], s[t]);
    }
}

// ---- V-prescale (in place): V' = V * sigG * rcp(colS) ----
__global__ void k_vprep(unsigned short* __restrict__ VpT,
                        const float* __restrict__ sigG,
                        const float* __restrict__ colS) {
    int row = blockIdx.x >> 1;
    int j0 = ((blockIdx.x & 1) * 256 + threadIdx.x) * 8;
    int h = row >> 5;
    unsigned short* p = VpT + (size_t)row * N + j0;
    short8 v = *(short8*)p;
    const float* sg = sigG + (size_t)h * N + j0;
    const float* cs = colS + (size_t)h * N + j0;
    float sc[8];
#pragma unroll
    for (int k = 0; k < 8; ++k)
        sc[k] = sg[k] * __builtin_amdgcn_rcpf(cs[k]);
    uint4v ov;
    ov[0] = packhu(bf2f((unsigned short)v[0]) * sc[0], bf2f((unsigned short)v[1]) * sc[1]);
    ov[1] = packhu(bf2f((unsigned short)v[2]) * sc[2], bf2f((unsigned short)v[3]) * sc[3]);
    ov[2] = packhu(bf2f((unsigned short)v[4]) * sc[4], bf2f((unsigned short)v[5]) * sc[5]);
    ov[3] = packhu(bf2f((unsigned short)v[6]) * sc[6], bf2f((unsigned short)v[7]) * sc[7]);
    *(uint4v*)p = ov;
}

// Assemble PV A-frag in registers from swapped-QK outputs (layout proven r10).
static __device__ __forceinline__ short8 frag_dance(f32x4 Sa, f32x4 Sb) {
    unsigned A0 = packhu(__builtin_amdgcn_exp2f(Sa[0]), __builtin_amdgcn_exp2f(Sa[1]));
    unsigned A1 = packhu(__builtin_amdgcn_exp2f(Sa[2]), __builtin_amdgcn_exp2f(Sa[3]));
    unsigned B0 = packhu(__builtin_amdgcn_exp2f(Sb[0]), __builtin_amdgcn_exp2f(Sb[1]));
    unsigned B1 = packhu(__builtin_amdgcn_exp2f(Sb[2]), __builtin_amdgcn_exp2f(Sb[3]));
    uint2v r1 = __builtin_amdgcn_permlane32_swap(A0, B0, false, false);
    uint2v r2 = __builtin_amdgcn_permlane16_swap(r1[0], r1[1], false, false); // dw0, dw2
    uint2v r3 = __builtin_amdgcn_permlane32_swap(A1, B1, false, false);
    uint2v r4 = __builtin_amdgcn_permlane16_swap(r3[0], r3[1], false, false); // dw1, dw3
    uint4v pu;
    pu[0] = r2[0]; pu[1] = r4[0]; pu[2] = r2[1]; pu[3] = r4[1];
    return __builtin_bit_cast(short8, pu);
}

// ---- pass 2: async global_load_lds double-buffered K/V slabs ----
// grid (16, NH, CH), 256 thr (4 waves): wave w owns i-tile [bx*256+64w, +64).
// Slab = 32 j: K 2KB + V' 2KB. Wave w DMAs its 1KB quarter each iter (zero
// VGPR cost); chunk index pre-swizzled (c ^= (r+(r>>2))&3) so ds_read_b128
// frags are 2-way-bank = free. __syncthreads drains vmcnt (compiler-emitted).
__global__ __launch_bounds__(256) void k_pass2(const unsigned short* __restrict__ Qp,
                                               const unsigned short* __restrict__ Kp,
                                               const unsigned short* __restrict__ VpT,
                                               unsigned short* __restrict__ Vpb) {
    __shared__ __align__(16) char smem[2][4096];
    int w = threadIdx.x >> 6, l = threadIdx.x & 63;
    int il = l & 15, g = l >> 4;
    int h = blockIdx.y;
    int i0 = blockIdx.x * 256 + w * 64;
    int jbeg = blockIdx.z * JSPAN;
    const unsigned short* Qh = Qp + (size_t)h * N * HD;
    const char* Khc = (const char*)(Kp + ((size_t)h * N + jbeg) * HD);
    const char* Vhc = (const char*)(VpT + (size_t)h * HD * N + jbeg);
    // per-lane DMA source (pre-swizzled chunk) + per-wave LDS quarter
    const char* gsrc;
    int gstep;
    {
        int s = (w & 1) * 64 + l;
        int r = s >> 2, c = s & 3;
        int cs = c ^ ((r + (r >> 2)) & 3);
        if (w < 2) { gsrc = Khc + r * 64 + cs * 16;           gstep = 2048; }
        else       { gsrc = Vhc + (size_t)r * 8192 + cs * 16; gstep = 64;  }
    }
    char* lq0 = smem[0] + w * 1024;
    char* lq1 = smem[1] + w * 1024;
    // swizzled frag read offset (row il, chunk g)
    int fo = il * 64 + ((g ^ ((il + (il >> 2)) & 3)) << 4);
    short8 Qf[4];
#pragma unroll
    for (int q = 0; q < 4; ++q)
        Qf[q] = *(const short8*)(Qh + (size_t)(i0 + q * 16 + il) * HD + g * 8);
    f32x4 z = {0.f, 0.f, 0.f, 0.f};
    f32x4 acc[4][2];
#pragma unroll
    for (int q = 0; q < 4; ++q) { acc[q][0] = z; acc[q][1] = z; }
    // prologue: DMA slab 0
    GLOAD(gsrc, lq0);
    gsrc += gstep;
    __syncthreads();
#pragma unroll
    for (int it = 0; it < 8; ++it) {
        int b = it & 1;
        // DMA next slab into the other buffer (it=7 over-issue stays in ws: safe)
        GLOAD(gsrc, b ? lq0 : lq1);
        gsrc += gstep;
        __builtin_amdgcn_sched_barrier(0);
        const char* kb = smem[b];
        short8 cK0 = *(const short8*)(kb + fo);
        short8 cK1 = *(const short8*)(kb + 1024 + fo);
        short8 cV0 = *(const short8*)(kb + 2048 + fo);
        short8 cV1 = *(const short8*)(kb + 3072 + fo);
        __builtin_amdgcn_s_setprio(1);
#pragma unroll
        for (int q = 0; q < 4; ++q) {
            // swapped QK: lane(il,g) gets S[j=4g+r][i=il]
            f32x4 SA = __builtin_amdgcn_mfma_f32_16x16x32_bf16(cK0, Qf[q], z, 0, 0, 0);
            f32x4 SB = __builtin_amdgcn_mfma_f32_16x16x32_bf16(cK1, Qf[q], z, 0, 0, 0);
            short8 Pa = frag_dance(SA, SB);
            acc[q][0] = __builtin_amdgcn_mfma_f32_16x16x32_bf16(Pa, cV0, acc[q][0], 0, 0, 0);
            acc[q][1] = __builtin_amdgcn_mfma_f32_16x16x32_bf16(Pa, cV1, acc[q][1], 0, 0, 0);
        }
        __builtin_amdgcn_s_setprio(0);
        __syncthreads();   // drains vmcnt(0) + lgkmcnt(0), publishes next slab
    }
    unsigned short* Vout = Vpb + (size_t)(blockIdx.z * NH + h) * N * HD;
#pragma unroll
    for (int q = 0; q < 4; ++q) {
#pragma unroll
        for (int r = 0; r < 4; ++r) {
            int ia = i0 + q * 16 + g * 4 + r;
            Vout[(size_t)ia * HD + il]      = f2bf(acc[q][0][r]);
            Vout[(size_t)ia * HD + 16 + il] = f2bf(acc[q][1][r]);
        }
    }
}

// ---- layernorm: sum CH bf16 partials (layout [ch][h][i][d]), normalize ----
__global__ __launch_bounds__(256) void k_ln(const unsigned short* __restrict__ Vpb,
                                            const float* __restrict__ gam,
                                            const float* __restrict__ bet,
                                            float* __restrict__ out) {
    int w = threadIdx.x >> 6, l = threadIdx.x & 63;
    int i = blockIdx.x * 4 + w;
    int h = l >> 3, d0 = (l & 7) << 2;   // lane owns channels c = (d0+r)*8 + h
    f32x4 x = {0.f, 0.f, 0.f, 0.f};
#pragma unroll
    for (int c = 0; c < CH; ++c) {
        short4v v = *(const short4v*)(Vpb + ((size_t)(c * NH + h) * N + i) * HD + d0);
        x[0] += bf2f((unsigned short)v[0]); x[1] += bf2f((unsigned short)v[1]);
        x[2] += bf2f((unsigned short)v[2]); x[3] += bf2f((unsigned short)v[3]);
    }
    float s1 = x[0] + x[1] + x[2] + x[3];
    float s2 = x[0] * x[0] + x[1] * x[1] + x[2] * x[2] + x[3] * x[3];
#pragma unroll
    for (int off = 1; off < 64; off <<= 1) {
        s1 += __shfl_xor(s1, off);
        s2 += __shfl_xor(s2, off);
    }
    float mu = s1 * (1.f / 256.f);
    float var = s2 * (1.f / 256.f) - mu * mu;
    float rs = rsqrtf(var + 1e-3f);
#pragma unroll
    for (int r = 0; r < 4; ++r) {
        int c = (d0 + r) * 8 + h;
        out[(size_t)i * HID + c] = (x[r] - mu) * rs * gam[c] + bet[c];
    }
}

extern "C" void kernel_launch(void* const* d_in, const int* in_sizes, int n_in,
                              void* d_out, int out_size, void* d_ws, size_t ws_size,
                              hipStream_t stream) {
    const float* feat = (const float*)d_in[0];
    const float* Wq   = (const float*)d_in[1];
    const float* bq   = (const float*)d_in[2];
    const float* Wkv  = (const float*)d_in[3];
    const float* bkv  = (const float*)d_in[4];
    const float* Weg  = (const float*)d_in[5];
    const float* beg  = (const float*)d_in[6];
    const float* ln_g = (const float*)d_in[7];
    const float* ln_b = (const float*)d_in[8];
    float* out = (float*)d_out;

    char* ws = (char*)d_ws;
    unsigned short* Qp    = (unsigned short*)(ws + 0);                     // 2 MB
    unsigned short* Kp    = (unsigned short*)(ws + (2u << 20));            // 2 MB
    unsigned short* VpT   = (unsigned short*)(ws + (4u << 20));            // 2 MB
    unsigned short* featb = (unsigned short*)(ws + (6u << 20));            // 2 MB
    unsigned short* WbT   = (unsigned short*)(ws + (8u << 20));            // 0.4 MB
    float* bC   = (float*)(ws + (8u << 20) + (512u << 10));                // 3 KB
    float* sigG = (float*)(ws + (8u << 20) + (528u << 10));                // 128 KB
    float* colS = (float*)(ws + (8u << 20) + (656u << 10));                // 128 KB
    unsigned short* Vpb = (unsigned short*)(ws + (9u << 20));              // CH*2 MB = 32 MB

    k_prep<<<dim3(1024 + NC), 256, 0, stream>>>(feat, Wq, Wkv, Weg, bq, bkv, beg,
                                                featb, WbT, bC, colS);
    k_proj<<<dim3(49, 64), 256, 0, stream>>>(featb, WbT, bC, Qp, Kp, VpT, sigG);
    k_pass1<<<dim3(16, NH, 32), 256, 0, stream>>>(Qp, Kp, colS);
    k_vprep<<<dim3(512), 256, 0, stream>>>(VpT, sigG, colS);
    k_pass2<<<dim3(16, NH, CH), 256, 0, stream>>>(Qp, Kp, VpT, Vpb);
    k_ln<<<dim3(1024), 256, 0, stream>>>(Vpb, ln_g, ln_b, out);
}